// Round 1
// baseline (21.722 us; speedup 1.0000x reference)
//
#include <hip/hip_runtime.h>

// TensorCPFactorization: value[b] = sum_r prod_i f_i[idx[b,i], r]
// DIM=512, RANK=256, ORDER=4, BATCH=100000, f32 factors.
//
// Strategy: one wave64 per batch element. The 4 row indices are uniform
// across the wave, so each factor-row read is 64 lanes x float4 = 1 KB
// fully-coalesced (exactly one row of 256 f32). Factors total 2 MB ->
// L2-resident; expected regime is L2-BW-bound (~400 MB of L2 reads).

#define RANK 256

__global__ __launch_bounds__(256) void cp_gather_kernel(
    const float* __restrict__ f0, const float* __restrict__ f1,
    const float* __restrict__ f2, const float* __restrict__ f3,
    const int*   __restrict__ idx,
    float*       __restrict__ out, int batch)
{
    const int wave = (int)((blockIdx.x * blockDim.x + threadIdx.x) >> 6);
    const int lane = (int)(threadIdx.x & 63);
    if (wave >= batch) return;

    // 4 indices for this element — same address across the wave (broadcast).
    const int4 iv = *reinterpret_cast<const int4*>(idx + wave * 4);

    const int r = lane * 4;
    const float4 a = *reinterpret_cast<const float4*>(f0 + (size_t)iv.x * RANK + r);
    const float4 b = *reinterpret_cast<const float4*>(f1 + (size_t)iv.y * RANK + r);
    const float4 c = *reinterpret_cast<const float4*>(f2 + (size_t)iv.z * RANK + r);
    const float4 d = *reinterpret_cast<const float4*>(f3 + (size_t)iv.w * RANK + r);

    float s = a.x * b.x * c.x * d.x
            + a.y * b.y * c.y * d.y
            + a.z * b.z * c.z * d.z
            + a.w * b.w * c.w * d.w;

    // wave-64 butterfly reduction
    #pragma unroll
    for (int off = 32; off > 0; off >>= 1)
        s += __shfl_down(s, off);

    if (lane == 0) out[wave] = s;
}

extern "C" void kernel_launch(void* const* d_in, const int* in_sizes, int n_in,
                              void* d_out, int out_size, void* d_ws, size_t ws_size,
                              hipStream_t stream) {
    const float* f0  = (const float*)d_in[0];
    const float* f1  = (const float*)d_in[1];
    const float* f2  = (const float*)d_in[2];
    const float* f3  = (const float*)d_in[3];
    const int*   idx = (const int*)d_in[4];
    float* out = (float*)d_out;

    const int batch = out_size;              // one output per batch element
    const int threads = 256;                 // 4 waves / block
    const int waves_per_block = threads / 64;
    const int grid = (batch + waves_per_block - 1) / waves_per_block;

    cp_gather_kernel<<<grid, threads, 0, stream>>>(f0, f1, f2, f3, idx, out, batch);
}

// Round 2
// 21.435 us; speedup vs baseline: 1.0134x; 1.0134x over previous
//
#include <hip/hip_runtime.h>

// TensorCPFactorization: value[b] = sum_r prod_i f_i[idx[b,i], r]
// DIM=512, RANK=256, ORDER=4, BATCH=100000, f32 factors.
//
// R1: one wave64 per 4 batch elements. The 4 row indices of each element are
// wave-uniform, so each factor-row read is 64 lanes x float4 = 1 KB fully
// coalesced (exactly one 256-f32 row). 16 loads issued up front per wave
// (4x MLP vs R0), 4 independent shuffle-reduction chains hide DS latency,
// and the 4 contiguous outputs store as a single float4 from lane 0.

#define RANK 256
#define EPW  4   // elements per wave

__global__ __launch_bounds__(256) void cp_gather_kernel(
    const float* __restrict__ f0, const float* __restrict__ f1,
    const float* __restrict__ f2, const float* __restrict__ f3,
    const int*   __restrict__ idx,
    float*       __restrict__ out, int batch)
{
    const int wid  = (int)((blockIdx.x * blockDim.x + threadIdx.x) >> 6);
    const int lane = (int)(threadIdx.x & 63);
    const int e0   = wid * EPW;
    if (e0 >= batch) return;   // batch % EPW == 0 (100000 % 4), no partial waves

    const int r = lane * 4;

    // Index vectors for the 4 elements (wave-uniform broadcast loads).
    int4 iv[EPW];
    #pragma unroll
    for (int e = 0; e < EPW; ++e)
        iv[e] = *reinterpret_cast<const int4*>(idx + (size_t)(e0 + e) * 4);

    // Issue all 16 row loads before any compute -> 16 outstanding VMEM ops.
    float4 rows[EPW][4];
    #pragma unroll
    for (int e = 0; e < EPW; ++e) {
        rows[e][0] = *reinterpret_cast<const float4*>(f0 + (size_t)iv[e].x * RANK + r);
        rows[e][1] = *reinterpret_cast<const float4*>(f1 + (size_t)iv[e].y * RANK + r);
        rows[e][2] = *reinterpret_cast<const float4*>(f2 + (size_t)iv[e].z * RANK + r);
        rows[e][3] = *reinterpret_cast<const float4*>(f3 + (size_t)iv[e].w * RANK + r);
    }

    // Per-lane 4-wide dot for each element.
    float s[EPW];
    #pragma unroll
    for (int e = 0; e < EPW; ++e) {
        const float4 a = rows[e][0], b = rows[e][1], c = rows[e][2], d = rows[e][3];
        s[e] = a.x * b.x * c.x * d.x
             + a.y * b.y * c.y * d.y
             + a.z * b.z * c.z * d.z
             + a.w * b.w * c.w * d.w;
    }

    // 4 independent 64-lane butterfly reductions (chains interleave -> DS
    // latency hidden).
    #pragma unroll
    for (int off = 32; off > 0; off >>= 1) {
        #pragma unroll
        for (int e = 0; e < EPW; ++e)
            s[e] += __shfl_xor(s[e], off);
    }

    if (lane == 0)
        *reinterpret_cast<float4*>(out + e0) = make_float4(s[0], s[1], s[2], s[3]);
}

extern "C" void kernel_launch(void* const* d_in, const int* in_sizes, int n_in,
                              void* d_out, int out_size, void* d_ws, size_t ws_size,
                              hipStream_t stream) {
    const float* f0  = (const float*)d_in[0];
    const float* f1  = (const float*)d_in[1];
    const float* f2  = (const float*)d_in[2];
    const float* f3  = (const float*)d_in[3];
    const int*   idx = (const int*)d_in[4];
    float* out = (float*)d_out;

    const int batch = out_size;                    // one output per element
    const int threads = 256;                       // 4 waves / block
    const int elems_per_block = (threads / 64) * EPW;  // 16
    const int grid = (batch + elems_per_block - 1) / elems_per_block;

    cp_gather_kernel<<<grid, threads, 0, stream>>>(f0, f1, f2, f3, idx, out, batch);
}